// Round 1
// baseline (201.202 us; speedup 1.0000x reference)
//
#include <hip/hip_runtime.h>
#include <math.h>

// DigitCaps dynamic routing, B=256 R=1152 C=10 OUT=16 IN=8, fp32.
// Key identity: b_ij(t) = dot(u_hat[b,r,c,:], Vsum[b,c,:]) with Vsum = sum of
// previous v iterates -> never store b_ij or u_hat; recompute u_hat per
// iteration from W (LDS-staged) and x.
//
// ws layout (needs >= 6.06 MB):
//   s_part[36][256][160] f32  (per-r-chunk partial s)   5.90 MB
//   Vsum  [256][160]     f32                            0.16 MB

namespace {
constexpr int Bdim = 256;
constexpr int Rdim = 1152;
constexpr int Cdim = 10;
constexpr int Odim = 16;
constexpr int Idim = 8;
constexpr int CO   = Cdim * Odim;   // 160

constexpr int NCH  = 36;            // r-chunks -> partial buffers
constexpr int RSUB = 8;             // rows staged in LDS per sub-step
constexpr int NSUB = 4;             // sub-steps per chunk (32 rows/chunk)
constexpr int BB   = 8;             // batch elements per block (4 bq * 2 Tb)
constexpr int NT   = 320;           // 5 waves
constexpr int WPAD = 132;           // padded floats per (r,c) slice in LDS
}

template<bool FIRST>
__global__ __launch_bounds__(NT)
void caps_iter(const float* __restrict__ x, const float* __restrict__ W,
               const float* __restrict__ Vsum, float* __restrict__ s_part)
{
    __shared__ float Wl[RSUB * Cdim * WPAD];      // 42.2 KB
    __shared__ float Lg[RSUB * 4 * 2 * Cdim];     // 2.5 KB logit exchange
    __shared__ float Vsl[BB * CO];                // 5 KB

    const int tid = threadIdx.x;
    const int bq  = tid / 80;        // 0..3
    const int g   = tid % 80;
    const int c   = g / 8;           // 0..9
    const int rl  = g % 8;           // 0..7  (== lane % 8: 80 % 8 == 0)

    const int chunk = blockIdx.x;            // 0..35
    const int bbase = blockIdx.y * BB;       // step 8
    const int b0    = bbase + bq * 2;        // this thread's two batches: b0, b0+1

    if (!FIRST) {
        for (int t = tid; t < BB * CO; t += NT)
            Vsl[t] = Vsum[bbase * CO + t];
    }

    float s0[Odim], s1[Odim];
#pragma unroll
    for (int o = 0; o < Odim; ++o) { s0[o] = 0.f; s1[o] = 0.f; }

    for (int sub = 0; sub < NSUB; ++sub) {
        const int r0 = chunk * (RSUB * NSUB) + sub * RSUB;

        __syncthreads();   // previous sub's LDS reads done (also Vsl visible on sub 0)

        // stage W[r0 .. r0+7][*][*][*] -> LDS, padded to WPAD per (r,c)
        const float4* src4 =
            reinterpret_cast<const float4*>(W + (size_t)r0 * (Cdim * Odim * Idim));
        for (int t4 = tid; t4 < RSUB * Cdim * 32; t4 += NT) {
            const int rc = t4 >> 5;          // which (r,c), 0..79
            const int wi = t4 & 31;          // float4 index within 128 floats
            reinterpret_cast<float4*>(Wl + rc * WPAD)[wi] = src4[t4];
        }
        __syncthreads();

        const int r = r0 + rl;
        const float4* xp0 = reinterpret_cast<const float4*>(x + ((size_t)b0 * Rdim + r) * Idim);
        const float4* xp1 = reinterpret_cast<const float4*>(x + ((size_t)(b0 + 1) * Rdim + r) * Idim);
        const float4 xa0 = xp0[0], xb0 = xp0[1];
        const float4 xa1 = xp1[0], xb1 = xp1[1];

        float u0[Odim], u1[Odim];
        const float4* wp4 = reinterpret_cast<const float4*>(Wl + (rl * Cdim + c) * WPAD);
#pragma unroll
        for (int o = 0; o < Odim; ++o) {
            const float4 wa = wp4[o * 2];
            const float4 wb = wp4[o * 2 + 1];
            u0[o] = wa.x * xa0.x + wa.y * xa0.y + wa.z * xa0.z + wa.w * xa0.w
                  + wb.x * xb0.x + wb.y * xb0.y + wb.z * xb0.z + wb.w * xb0.w;
            u1[o] = wa.x * xa1.x + wa.y * xa1.y + wa.z * xa1.z + wa.w * xa1.w
                  + wb.x * xb1.x + wb.y * xb1.y + wb.z * xb1.z + wb.w * xb1.w;
        }

        float cw0, cw1;
        if (FIRST) {
            cw0 = 0.1f; cw1 = 0.1f;   // softmax of zeros over C=10
        } else {
            float l0 = 0.f, l1 = 0.f;
            const float* v0p = Vsl + (bq * 2 + 0) * CO + c * Odim;
            const float* v1p = v0p + CO;
#pragma unroll
            for (int o = 0; o < Odim; ++o) { l0 += u0[o] * v0p[o]; l1 += u1[o] * v1p[o]; }

            float* lp = Lg + ((rl * 4 + bq) * 2) * Cdim;
            lp[c] = l0;
            lp[Cdim + c] = l1;
            __syncthreads();

            float m0 = -1e30f, m1 = -1e30f;
#pragma unroll
            for (int cc = 0; cc < Cdim; ++cc) {
                m0 = fmaxf(m0, lp[cc]);
                m1 = fmaxf(m1, lp[Cdim + cc]);
            }
            float d0 = 0.f, d1 = 0.f;
#pragma unroll
            for (int cc = 0; cc < Cdim; ++cc) {
                d0 += __expf(lp[cc] - m0);
                d1 += __expf(lp[Cdim + cc] - m1);
            }
            cw0 = __expf(l0 - m0) / d0;
            cw1 = __expf(l1 - m1) / d1;
            // no barrier needed here: next Lg write is preceded by two syncthreads
        }

#pragma unroll
        for (int o = 0; o < Odim; ++o) { s0[o] += cw0 * u0[o]; s1[o] += cw1 * u1[o]; }
    }

    // reduce over rl (8 consecutive lanes) via shuffle
#pragma unroll
    for (int o = 0; o < Odim; ++o) {
        float v0 = s0[o], v1 = s1[o];
        v0 += __shfl_xor(v0, 1); v0 += __shfl_xor(v0, 2); v0 += __shfl_xor(v0, 4);
        v1 += __shfl_xor(v1, 1); v1 += __shfl_xor(v1, 2); v1 += __shfl_xor(v1, 4);
        s0[o] = v0; s1[o] = v1;
    }

    if (rl == 0) {
        float* dst0 = s_part + ((size_t)chunk * Bdim + b0) * CO + c * Odim;
        float* dst1 = dst0 + CO;
#pragma unroll
        for (int q = 0; q < 4; ++q) {
            reinterpret_cast<float4*>(dst0)[q] =
                make_float4(s0[q * 4], s0[q * 4 + 1], s0[q * 4 + 2], s0[q * 4 + 3]);
            reinterpret_cast<float4*>(dst1)[q] =
                make_float4(s1[q * 4], s1[q * 4 + 1], s1[q * 4 + 2], s1[q * 4 + 3]);
        }
    }
}

// Sum the NCH partials, squash, then either accumulate Vsum or emit output.
template<bool LAST>
__global__ __launch_bounds__(256)
void caps_reduce(const float* __restrict__ s_part, float* __restrict__ Vsum,
                 float* __restrict__ out)
{
    const int idx = blockIdx.x * 256 + threadIdx.x;   // < 40960 = B*C*O
    float s = 0.f;
#pragma unroll 4
    for (int k = 0; k < NCH; ++k) s += s_part[(size_t)k * (Bdim * CO) + idx];

    // ||s||^2 over the 16-lane o-group (o = idx % 16 = lane % 16)
    float ssq = s * s;
    ssq += __shfl_xor(ssq, 1);
    ssq += __shfl_xor(ssq, 2);
    ssq += __shfl_xor(ssq, 4);
    ssq += __shfl_xor(ssq, 8);

    const float mag = sqrtf(ssq + 1e-8f);
    const float v = ssq / (1.f + ssq) * s / (mag + 1e-8f);

    if (LAST) out[idx] = v;
    else      Vsum[idx] += v;
}

extern "C" void kernel_launch(void* const* d_in, const int* in_sizes, int n_in,
                              void* d_out, int out_size, void* d_ws, size_t ws_size,
                              hipStream_t stream)
{
    const float* x = (const float*)d_in[0];   // [256,1152,8]
    const float* W = (const float*)d_in[1];   // [1152,10,16,8]
    float* out = (float*)d_out;               // [256,10,16]

    float* s_part = (float*)d_ws;                       // 36*256*160 f32
    float* Vsum   = s_part + (size_t)NCH * Bdim * CO;   // 256*160 f32

    hipMemsetAsync(Vsum, 0, (size_t)Bdim * CO * sizeof(float), stream);

    const dim3 gi(NCH, Bdim / BB);
    const dim3 bi(NT);
    const dim3 gr((Bdim * CO) / 256);
    const dim3 br(256);

    // it 0
    caps_iter<true><<<gi, bi, 0, stream>>>(x, W, Vsum, s_part);
    caps_reduce<false><<<gr, br, 0, stream>>>(s_part, Vsum, out);
    // it 1
    caps_iter<false><<<gi, bi, 0, stream>>>(x, W, Vsum, s_part);
    caps_reduce<false><<<gr, br, 0, stream>>>(s_part, Vsum, out);
    // it 2 (final -> d_out)
    caps_iter<false><<<gi, bi, 0, stream>>>(x, W, Vsum, s_part);
    caps_reduce<true><<<gr, br, 0, stream>>>(s_part, Vsum, out);
}